// Round 3
// baseline (365.645 us; speedup 1.0000x reference)
//
#include <hip/hip_runtime.h>
#include <hip/hip_bf16.h>
#include <stdint.h>

#define B_ROWS 16384
#define IN_DIM 2048
#define OUT_DIM 2048

typedef __attribute__((ext_vector_type(4))) float f32x4;
typedef __attribute__((ext_vector_type(8))) short s16x8;

__device__ __forceinline__ unsigned short f2bf_rne(float f) {
  union { float f; unsigned u; } c; c.f = f;
  unsigned u = c.u;
  return (unsigned short)((u + 0x7FFFu + ((u >> 16) & 1u)) >> 16);
}

// Fused prep: blocks [0, 4096) handle x (one WAVE per row: bf16 cast + L2 norm);
// blocks [4096, 6144) handle W (fp32 -> bf16, 8 elems/thread).  UNCHANGED.
#define PREP_X_BLOCKS 4096
#define PREP_W_BLOCKS 2048

__global__ void __launch_bounds__(256) prep_kernel(const float* __restrict__ x,
                                                   unsigned short* __restrict__ xn,
                                                   float* __restrict__ scale,
                                                   const float* __restrict__ W,
                                                   unsigned short* __restrict__ Wb) {
  if (blockIdx.x < PREP_X_BLOCKS) {
    const int row  = (blockIdx.x * 256 + threadIdx.x) >> 6;
    const int lane = threadIdx.x & 63;
    const float4* xr = (const float4*)(x + (size_t)row * IN_DIM);
    unsigned short* xrow = xn + (size_t)row * IN_DIM;

    float ss = 0.0f;
    #pragma unroll
    for (int j = 0; j < 4; ++j) {
      const int f4 = j * 128 + lane * 2;   // float4 index within the row
      float4 v0 = xr[f4 + 0];
      float4 v1 = xr[f4 + 1];
      ss += v0.x * v0.x + v0.y * v0.y + v0.z * v0.z + v0.w * v0.w +
            v1.x * v1.x + v1.y * v1.y + v1.z * v1.z + v1.w * v1.w;
      s16x8 p;
      p[0] = (short)f2bf_rne(v0.x); p[1] = (short)f2bf_rne(v0.y);
      p[2] = (short)f2bf_rne(v0.z); p[3] = (short)f2bf_rne(v0.w);
      p[4] = (short)f2bf_rne(v1.x); p[5] = (short)f2bf_rne(v1.y);
      p[6] = (short)f2bf_rne(v1.z); p[7] = (short)f2bf_rne(v1.w);
      *(s16x8*)(xrow + f4 * 4) = p;
    }

    #pragma unroll
    for (int m = 32; m > 0; m >>= 1) ss += __shfl_xor(ss, m, 64);
    if (lane == 0) scale[row] = 1.0f / (sqrtf(ss) + 1e-4f);
  } else {
    const size_t base = (size_t)(blockIdx.x - PREP_X_BLOCKS) * 2048 +
                        (size_t)threadIdx.x * 8;
    const float4* wp = (const float4*)(W + base);
    float4 v0 = wp[0];
    float4 v1 = wp[1];
    s16x8 p;
    p[0] = (short)f2bf_rne(v0.x); p[1] = (short)f2bf_rne(v0.y);
    p[2] = (short)f2bf_rne(v0.z); p[3] = (short)f2bf_rne(v0.w);
    p[4] = (short)f2bf_rne(v1.x); p[5] = (short)f2bf_rne(v1.y);
    p[6] = (short)f2bf_rne(v1.z); p[7] = (short)f2bf_rne(v1.w);
    *(s16x8*)(Wb + base) = p;
  }
}

// ===========================================================================
// 256x256 tile, BK=64, 512 threads (8 waves 2Mx4N), per-wave 128x64, acc[8][4].
// PIPELINED 4-phase schedule: each phase issues the ds_reads for the NEXT
// phase's MFMA group, then runs the CURRENT group's MFMA on registers loaded
// one phase ago -> the ~768-cyc LDS drain hides under the ~620-cyc MFMA
// cluster.  (R1/R2 post-mortem: any schedule where read-issue is adjacent to
// its lgkm-consume serializes LDS and matrix pipes -> stuck at 41% MfmaUtil.)
// A-frags ping-pong aP/aQ (no WAR); bf[ni][kk] persists across the tile.
//   p1: issue R2(T)=A.msub0.kk1+B.kk1 | GLD A-even(T+1) | MFMA G1: aP x bf[.][0]
//       | vmcnt(4) barrier
//   p2: issue R3(T)=A.msub1.kk0       | GLD B-h1 (T+1) | MFMA G2: aQ x bf[.][1]
//   p3: issue R4(T)=A.msub1.kk1       | GLD A-odd (T+1) | MFMA G3: aP x bf[.][0]
//       | vmcnt(2) barrier
//   p4: issue R1(T+1)=A.msub0.kk0+B.kk0 (from buf nxt!) | GLD B-h0(T+2) ->
//       buf[cur] | MFMA G4: aQ x bf[.][1]
// Only 2 barriers per K-tile (the two vmcnt fence points); all LDS WAR pairs
// re-verified: every GLD write is issued after a barrier that post-dates the
// last read of its region (reads complete before their consuming MFMA, which
// precedes the barrier).  vmcnt ledger (issue order Ao(T)@p3(T-1),
// Bh0(T+1)@p4(T-1), Ae(T+1)@p1(T), Bh1(T+1)@p2(T), Ao(T+1)@p3(T), ...):
//   end-p1(T): outstanding 6 -> vmcnt(4): Ao(T) done  (feeds R3/R4 @p2/p3)
//   end-p3(T): outstanding 8 -> vmcnt(2): Bh0/Ae/Bh1(T+1) done (feeds R1/R2)
// Never vmcnt(0) in the loop; the asm "memory" clobbers double as the fences
// that keep ds_reads from hoisting above the sync points.  Dead prefetches at
// T=30/31 clamp to k=0 (keeps vmcnt counts exact; garbage lands in regions
// never consumed).  LDS XOR-8 chunk swizzle unchanged (0 bank conflicts).
// ===========================================================================

#define GLD16(SRC, DST)                                                        \
  __builtin_amdgcn_global_load_lds(                                            \
      (const __attribute__((address_space(1))) unsigned int*)(SRC),            \
      (__attribute__((address_space(3))) unsigned int*)(DST), 16, 0, 0)

__global__ void __launch_bounds__(512, 1) gemm_kernel(const unsigned short* __restrict__ A,
                                                      const unsigned short* __restrict__ Bm,
                                                      const float* __restrict__ scale,
                                                      const float* __restrict__ bias,
                                                      float* __restrict__ out) {
  __shared__ unsigned short As[2][256 * 64];
  __shared__ unsigned short Bs[2][256 * 64];

  const int tid = threadIdx.x;
  const int bid = blockIdx.x;
  // XCD swizzle: round-robin dispatch -> bid&7 is the XCD. Each XCD owns 8
  // consecutive bm (1MB A-slab in its L2) and sweeps all 8 bn.
  const int xcd = bid & 7;
  const int loc = bid >> 3;               // 0..63
  const int bm  = xcd * 8 + (loc >> 3);   // 0..63
  const int bn  = loc & 7;                // 0..7

  const int lane = tid & 63;
  const int wave = tid >> 6;              // 0..7
  const int wm   = wave >> 2;             // 0..1
  const int wn   = wave & 3;              // 0..3
  const int lrow = lane & 15;
  const int lq   = lane >> 4;

  // staging: thread t = row (t>>3), chunk (t&7) of a 64-row block;
  // LDS dest linear at byte t*16; global col pre-swizzled (XOR-8).
  const int sr = tid >> 3;
  const int sc = tid & 7;
  const unsigned short* aG = A  + (size_t)(bm * 256 + sr) * IN_DIM + ((sc ^ (sr & 7)) * 8);
  const unsigned short* bG = Bm + (size_t)(bn * 256 + sr) * IN_DIM + ((sc ^ (sr & 7)) * 8);

  // fragment read bases (element offsets into a 256x64 buffer)
  const int aRow = (wm * 128 + lrow) * 64;
  const int bRow = (wn * 64  + lrow) * 64;
  const int c0   = (lq ^ (lrow & 7)) * 8;   // kk=0 chunk; kk=1 chunk = c0^32

  f32x4 acc[8][4] = {};
  s16x8 aP[4], aQ[4];
  s16x8 bf[4][2];

  // --- prologue: stage tile 0 (B-h0,B-h1,A-even,A-odd) + B-h0(1)
  {
    char* aD = (char*)&As[0][0] + tid * 16;
    char* bD = (char*)&Bs[0][0] + tid * 16;
    char* bD1 = (char*)&Bs[1][0] + tid * 16;
    GLD16(bG,                         bD);           // B-h0(0)
    GLD16(bG + (size_t) 64 * IN_DIM,  bD + 8192);
    GLD16(bG + (size_t)128 * IN_DIM,  bD + 16384);   // B-h1(0)
    GLD16(bG + (size_t)192 * IN_DIM,  bD + 24576);
    GLD16(aG,                         aD);           // A-even(0): rows 0-63,128-191
    GLD16(aG + (size_t)128 * IN_DIM,  aD + 16384);
    GLD16(aG + (size_t) 64 * IN_DIM,  aD + 8192);    // A-odd(0): rows 64-127,192-255
    GLD16(aG + (size_t)192 * IN_DIM,  aD + 24576);
    GLD16(bG + 64,                        bD1);      // B-h0(1)
    GLD16(bG + 64 + (size_t)64 * IN_DIM,  bD1 + 8192);
  }
  asm volatile("s_waitcnt vmcnt(4)" ::: "memory");  // Bh0(0),Bh1(0),Ae(0) landed
  __builtin_amdgcn_s_barrier();

  // R1(0): aP <- A.msub0.kk0, bf[.][0] <- B.kk0  (buf0)
  #pragma unroll
  for (int mi = 0; mi < 4; ++mi)
    aP[mi] = *(const s16x8*)(&As[0][aRow + mi * 1024 + c0]);
  #pragma unroll
  for (int ni = 0; ni < 4; ++ni)
    bf[ni][0] = *(const s16x8*)(&Bs[0][bRow + ni * 1024 + c0]);

  for (int T = 0; T < IN_DIM / 64; ++T) {
    const int cur = T & 1, nxt = cur ^ 1;
    const unsigned short* Ac = &As[cur][0];
    const unsigned short* Bc = &Bs[cur][0];
    const unsigned short* An = &As[nxt][0];
    const unsigned short* Bn = &Bs[nxt][0];
    char* aD  = (char*)&As[nxt][0] + tid * 16;
    char* bD  = (char*)&Bs[nxt][0] + tid * 16;
    char* bDc = (char*)&Bs[cur][0] + tid * 16;     // B-h0(T+2) target = buf[cur]
    const size_t k1 = (size_t)((T < 31) ? (T + 1) * 64 : 0);  // dead at T=31
    const size_t k2 = (size_t)((T < 30) ? (T + 2) * 64 : 0);  // dead at T>=30

    // ---- p1: R2(T) | GLD A-even(T+1) | G1 | vmcnt(4) barrier
    #pragma unroll
    for (int mi = 0; mi < 4; ++mi)
      aQ[mi] = *(const s16x8*)(Ac + aRow + mi * 1024 + (c0 ^ 32));
    #pragma unroll
    for (int ni = 0; ni < 4; ++ni)
      bf[ni][1] = *(const s16x8*)(Bc + bRow + ni * 1024 + (c0 ^ 32));
    GLD16(aG + k1,                         aD);
    GLD16(aG + k1 + (size_t)128 * IN_DIM,  aD + 16384);
    __builtin_amdgcn_s_setprio(1);
    #pragma unroll
    for (int mi = 0; mi < 4; ++mi)
      #pragma unroll
      for (int ni = 0; ni < 4; ++ni)
        acc[mi][ni] = __builtin_amdgcn_mfma_f32_16x16x32_bf16(aP[mi], bf[ni][0], acc[mi][ni], 0, 0, 0);
    __builtin_amdgcn_s_setprio(0);
    asm volatile("s_waitcnt vmcnt(4)" ::: "memory");  // A-odd(T) landed
    __builtin_amdgcn_s_barrier();

    // ---- p2: R3(T) | GLD B-h1(T+1) | G2
    #pragma unroll
    for (int mi = 0; mi < 4; ++mi)
      aP[mi] = *(const s16x8*)(Ac + aRow + (4 + mi) * 1024 + c0);
    GLD16(bG + k1 + (size_t)128 * IN_DIM,  bD + 16384);
    GLD16(bG + k1 + (size_t)192 * IN_DIM,  bD + 24576);
    __builtin_amdgcn_s_setprio(1);
    #pragma unroll
    for (int mi = 0; mi < 4; ++mi)
      #pragma unroll
      for (int ni = 0; ni < 4; ++ni)
        acc[mi][ni] = __builtin_amdgcn_mfma_f32_16x16x32_bf16(aQ[mi], bf[ni][1], acc[mi][ni], 0, 0, 0);
    __builtin_amdgcn_s_setprio(0);

    // ---- p3: R4(T) | GLD A-odd(T+1) | G3 | vmcnt(2) barrier
    #pragma unroll
    for (int mi = 0; mi < 4; ++mi)
      aQ[mi] = *(const s16x8*)(Ac + aRow + (4 + mi) * 1024 + (c0 ^ 32));
    GLD16(aG + k1 + (size_t) 64 * IN_DIM,  aD + 8192);
    GLD16(aG + k1 + (size_t)192 * IN_DIM,  aD + 24576);
    __builtin_amdgcn_s_setprio(1);
    #pragma unroll
    for (int mi = 0; mi < 4; ++mi)
      #pragma unroll
      for (int ni = 0; ni < 4; ++ni)
        acc[4 + mi][ni] = __builtin_amdgcn_mfma_f32_16x16x32_bf16(aP[mi], bf[ni][0], acc[4 + mi][ni], 0, 0, 0);
    __builtin_amdgcn_s_setprio(0);
    asm volatile("s_waitcnt vmcnt(2)" ::: "memory");  // Bh0,Ae,Bh1(T+1) landed
    __builtin_amdgcn_s_barrier();

    // ---- p4: R1(T+1) from buf[nxt] | GLD B-h0(T+2) -> buf[cur] | G4
    #pragma unroll
    for (int mi = 0; mi < 4; ++mi)
      aP[mi] = *(const s16x8*)(An + aRow + mi * 1024 + c0);
    #pragma unroll
    for (int ni = 0; ni < 4; ++ni)
      bf[ni][0] = *(const s16x8*)(Bn + bRow + ni * 1024 + c0);
    GLD16(bG + k2,                         bDc);
    GLD16(bG + k2 + (size_t) 64 * IN_DIM,  bDc + 8192);
    __builtin_amdgcn_s_setprio(1);
    #pragma unroll
    for (int mi = 0; mi < 4; ++mi)
      #pragma unroll
      for (int ni = 0; ni < 4; ++ni)
        acc[4 + mi][ni] = __builtin_amdgcn_mfma_f32_16x16x32_bf16(aQ[mi], bf[ni][1], acc[4 + mi][ni], 0, 0, 0);
    __builtin_amdgcn_s_setprio(0);
  }

  // ---------- epilogue: D lane map col=lane&15, row=(lane>>4)*4 + r
  const int row0 = bm * 256 + wm * 128 + lq * 4;
  const int col0 = bn * 256 + wn * 64 + lrow;
  #pragma unroll
  for (int mi = 0; mi < 8; ++mi) {
    const int row = row0 + mi * 16;
    const f32x4 sc4 = *(const f32x4*)(scale + row);
    #pragma unroll
    for (int ni = 0; ni < 4; ++ni) {
      const int col = col0 + ni * 16;
      const float bcol = bias[col];
      #pragma unroll
      for (int r = 0; r < 4; ++r) {
        float v = acc[mi][ni][r] * sc4[r] + bcol;
        out[(size_t)(row + r) * OUT_DIM + col] = fmaxf(v, 0.0f);
      }
    }
  }
}

extern "C" void kernel_launch(void* const* d_in, const int* in_sizes, int n_in,
                              void* d_out, int out_size, void* d_ws, size_t ws_size,
                              hipStream_t stream) {
  const float* x = (const float*)d_in[0];
  const float* W = (const float*)d_in[1];
  const float* b = (const float*)d_in[2];
  float* out = (float*)d_out;

  char* ws = (char*)d_ws;
  unsigned short* xn    = (unsigned short*)ws;                                  // 67108864 B
  unsigned short* Wb    = (unsigned short*)(ws + (size_t)67108864);             //  8388608 B
  float*          scale = (float*)(ws + (size_t)67108864 + (size_t)8388608);    //    65536 B

  prep_kernel<<<PREP_X_BLOCKS + PREP_W_BLOCKS, 256, 0, stream>>>(x, xn, scale, W, Wb);

  gemm_kernel<<<(OUT_DIM / 256) * (B_ROWS / 256), 512, 0, stream>>>(xn, Wb, scale, b, out);
}

// Round 4
// 360.488 us; speedup vs baseline: 1.0143x; 1.0143x over previous
//
#include <hip/hip_runtime.h>
#include <hip/hip_bf16.h>
#include <stdint.h>

#define B_ROWS 16384
#define IN_DIM 2048
#define OUT_DIM 2048

typedef __attribute__((ext_vector_type(4))) float f32x4;
typedef __attribute__((ext_vector_type(8))) short s16x8;

__device__ __forceinline__ unsigned short f2bf_rne(float f) {
  union { float f; unsigned u; } c; c.f = f;
  unsigned u = c.u;
  return (unsigned short)((u + 0x7FFFu + ((u >> 16) & 1u)) >> 16);
}

// Fused prep: blocks [0, 4096) handle x (one WAVE per row: bf16 cast + L2 norm);
// blocks [4096, 6144) handle W (fp32 -> bf16, 8 elems/thread).  UNCHANGED.
#define PREP_X_BLOCKS 4096
#define PREP_W_BLOCKS 2048

__global__ void __launch_bounds__(256) prep_kernel(const float* __restrict__ x,
                                                   unsigned short* __restrict__ xn,
                                                   float* __restrict__ scale,
                                                   const float* __restrict__ W,
                                                   unsigned short* __restrict__ Wb) {
  if (blockIdx.x < PREP_X_BLOCKS) {
    const int row  = (blockIdx.x * 256 + threadIdx.x) >> 6;
    const int lane = threadIdx.x & 63;
    const float4* xr = (const float4*)(x + (size_t)row * IN_DIM);
    unsigned short* xrow = xn + (size_t)row * IN_DIM;

    float ss = 0.0f;
    #pragma unroll
    for (int j = 0; j < 4; ++j) {
      const int f4 = j * 128 + lane * 2;   // float4 index within the row
      float4 v0 = xr[f4 + 0];
      float4 v1 = xr[f4 + 1];
      ss += v0.x * v0.x + v0.y * v0.y + v0.z * v0.z + v0.w * v0.w +
            v1.x * v1.x + v1.y * v1.y + v1.z * v1.z + v1.w * v1.w;
      s16x8 p;
      p[0] = (short)f2bf_rne(v0.x); p[1] = (short)f2bf_rne(v0.y);
      p[2] = (short)f2bf_rne(v0.z); p[3] = (short)f2bf_rne(v0.w);
      p[4] = (short)f2bf_rne(v1.x); p[5] = (short)f2bf_rne(v1.y);
      p[6] = (short)f2bf_rne(v1.z); p[7] = (short)f2bf_rne(v1.w);
      *(s16x8*)(xrow + f4 * 4) = p;
    }

    #pragma unroll
    for (int m = 32; m > 0; m >>= 1) ss += __shfl_xor(ss, m, 64);
    if (lane == 0) scale[row] = 1.0f / (sqrtf(ss) + 1e-4f);
  } else {
    const size_t base = (size_t)(blockIdx.x - PREP_X_BLOCKS) * 2048 +
                        (size_t)threadIdx.x * 8;
    const float4* wp = (const float4*)(W + base);
    float4 v0 = wp[0];
    float4 v1 = wp[1];
    s16x8 p;
    p[0] = (short)f2bf_rne(v0.x); p[1] = (short)f2bf_rne(v0.y);
    p[2] = (short)f2bf_rne(v0.z); p[3] = (short)f2bf_rne(v0.w);
    p[4] = (short)f2bf_rne(v1.x); p[5] = (short)f2bf_rne(v1.y);
    p[6] = (short)f2bf_rne(v1.z); p[7] = (short)f2bf_rne(v1.w);
    *(s16x8*)(Wb + base) = p;
  }
}

// ===========================================================================
// Faithful port of the m201 256^2 8-phase template (2 K-tiles per iteration).
// 512 thr (8 waves 2Mx4N), per-wave C = 128x64, acc[8][4].  BK=64.
// LDS: As[2][2][128*64], Bs[2][2][128*64]  (=[Ktile parity][half]) = 128 KiB.
//   A-half h = tile rows {h*64..h*64+63, 128+h*64..}, packed 128 rows.
//   B-half h = tile rows with (r>>5)&1==h, packed pr=(r>>6)*32+(r&31).
// Per phase: {ds_read this phase's frags; stage ONE half-tile (2 GLD16);
//   [lgkmcnt(8) if 12 reads]; s_barrier; lgkmcnt(0)+sched_barrier(0) (rule
//   #18); setprio(1); 16 MFMA (one 64x32 C-quadrant x K=64); setprio(0);
//   [vmcnt(6) at ph4/ph8 ONLY]; s_barrier; sched_barrier(0)}.
// Frag reuse: A-half read once per 2 phases (8 reads), B-half once per K-tile
// (4 reads); phases p1/p5=12 reads, p2/p6=4, p3/p7=8, p4/p8=0.
// Stage schedule (iter i, t0=2i, t1=2i+1):  p1:A1(t1)  p2:A0(t0+2)
//   p3:B0(t0+2)  p4:B1(t0+2)  p5:A1(t0+2)  p6:A0(t1+2)  p7:B0(t1+2)
//   p8:B1(t1+2).   Ledger (2 loads/stage, vmcnt(6) at p4/p8 end):
//   every stage drains >=1 fence before its first read (A1(t1): p1->read p7,
//   fence p4; t0+2 stages: read iter i+1 p1-p3/p5, fences p8/p4(i+1)); every
//   stage overwrites a region whose last ds_read was >=1 phase earlier and
//   those reads are drained by that phase's lgkmcnt(0) before its closing
//   barrier -> no LDS WAR race.  Never vmcnt(0) in the loop; one vmcnt(0)
//   after the loop so dead tail prefetches can't land in a successor block's
//   LDS.  XOR-8 chunk swizzle per 128-row half-buffer (0 conflicts measured):
//   phys chunk = logical ^ (packed_row & 7), via pre-swizzled global column.
// ===========================================================================

#define GLD16(SRC, DST)                                                        \
  __builtin_amdgcn_global_load_lds(                                            \
      (const __attribute__((address_space(1))) unsigned int*)(SRC),            \
      (__attribute__((address_space(3))) unsigned int*)(DST), 16, 0, 0)

#define STAGE_A(par, h, kofs) do {                                             \
    char* d_ = (char*)&As[par][h][0] + tid * 16;                               \
    GLD16(aG + (kofs) + (size_t)((h) * 64) * IN_DIM,       d_);                \
    GLD16(aG + (kofs) + (size_t)((h) * 64 + 128) * IN_DIM, d_ + 8192);         \
  } while (0)

#define STAGE_B(par, h, kofs) do {                                             \
    char* d_ = (char*)&Bs[par][h][0] + tid * 16;                               \
    const unsigned short* s_ = (h) ? bG1 : bG0;                                \
    GLD16(s_ + (kofs),                          d_);                           \
    GLD16(s_ + (kofs) + (size_t)128 * IN_DIM,   d_ + 8192);                    \
  } while (0)

#define READ_A(par, mh) do {                                                   \
    _Pragma("unroll") for (int mi = 0; mi < 4; ++mi) {                         \
      af[mi][0] = *(const s16x8*)(&As[par][mh][aOff + mi * 1024 + c0]);        \
      af[mi][1] = *(const s16x8*)(&As[par][mh][aOff + mi * 1024 + (c0 ^ 32)]); \
    } } while (0)

#define READ_B(par, nh, dst) do {                                              \
    _Pragma("unroll") for (int ni = 0; ni < 2; ++ni) {                         \
      dst[ni][0] = *(const s16x8*)(&Bs[par][nh][bOff + ni * 1024 + c0]);       \
      dst[ni][1] = *(const s16x8*)(&Bs[par][nh][bOff + ni * 1024 + (c0 ^ 32)]);\
    } } while (0)

#define MFMA16(mh, nh, bfr) do {                                               \
    __builtin_amdgcn_s_setprio(1);                                             \
    _Pragma("unroll") for (int kk = 0; kk < 2; ++kk)                           \
    _Pragma("unroll") for (int mi = 0; mi < 4; ++mi)                           \
    _Pragma("unroll") for (int ni = 0; ni < 2; ++ni)                           \
      acc[(mh) * 4 + mi][(nh) * 2 + ni] =                                      \
          __builtin_amdgcn_mfma_f32_16x16x32_bf16(                             \
              af[mi][kk], bfr[ni][kk], acc[(mh) * 4 + mi][(nh) * 2 + ni],      \
              0, 0, 0);                                                        \
    __builtin_amdgcn_s_setprio(0);                                             \
  } while (0)

#define BAR()     __builtin_amdgcn_s_barrier()
#define SCHED0()  __builtin_amdgcn_sched_barrier(0)
#define LGKM0()   do { asm volatile("s_waitcnt lgkmcnt(0)" ::: "memory"); SCHED0(); } while (0)
#define LGKM8()   asm volatile("s_waitcnt lgkmcnt(8)" ::: "memory")
#define VM6()     asm volatile("s_waitcnt vmcnt(6)" ::: "memory")

__global__ void __launch_bounds__(512, 1) gemm_kernel(const unsigned short* __restrict__ A,
                                                      const unsigned short* __restrict__ Bm,
                                                      const float* __restrict__ scale,
                                                      const float* __restrict__ bias,
                                                      float* __restrict__ out) {
  __shared__ unsigned short As[2][2][128 * 64];   // [Ktile parity][m-half]
  __shared__ unsigned short Bs[2][2][128 * 64];   // [Ktile parity][n-half]

  const int tid = threadIdx.x;
  const int bid = blockIdx.x;
  // XCD swizzle (512 blocks, %8==0 -> bijective): bid&7 = XCD; each XCD owns
  // 8 consecutive bm (1MB A-slab in its L2) and sweeps all 8 bn.
  const int xcd = bid & 7;
  const int loc = bid >> 3;               // 0..63
  const int bm  = xcd * 8 + (loc >> 3);   // 0..63
  const int bn  = loc & 7;                // 0..7

  const int lane = tid & 63;
  const int wave = tid >> 6;              // 0..7
  const int wm   = wave >> 2;             // 0..1
  const int wn   = wave & 3;              // 0..3
  const int lrow = lane & 15;
  const int lq   = lane >> 4;

  // staging: thread t -> packed row sr=t>>3 (0..63), chunk sc=t&7; LDS dest
  // linear at t*16 within each half-buffer; global col pre-swizzled (XOR-8).
  const int sr = tid >> 3;
  const int sc = tid & 7;
  const size_t swz = (size_t)((sc ^ (sr & 7)) * 8);
  const unsigned short* aG  = A  + (size_t)(bm * 256 + sr) * IN_DIM + swz;
  const unsigned short* bG0 = Bm + (size_t)(bn * 256 + (sr >> 5) * 64 + (sr & 31)) * IN_DIM + swz;
  const unsigned short* bG1 = bG0 + (size_t)32 * IN_DIM;

  // fragment read bases (element offsets into a [128][64] half-buffer)
  const int aOff = (wm * 64 + lrow) * 64;   // + mi*1024 + chunk
  const int bOff = (wn * 32 + lrow) * 64;   // + ni*1024 + chunk
  const int c0   = (lq ^ (lrow & 7)) * 8;   // kk0 chunk; kk1 = c0^32

  f32x4 acc[8][4] = {};
  s16x8 af[4][2], b0[2][2], b1[2][2];

  // --- prologue: A0(0),B0(0),B1(0),A1(0),A0(1),B0(1),B1(1); NOT A1(1) (p1 does)
  STAGE_A(0, 0, (size_t)0);
  STAGE_B(0, 0, (size_t)0);
  STAGE_B(0, 1, (size_t)0);
  STAGE_A(0, 1, (size_t)0);
  STAGE_A(1, 0, (size_t)64);
  STAGE_B(1, 0, (size_t)64);
  STAGE_B(1, 1, (size_t)64);
  VM6();           // first 8 loads (all of K-tile 0) landed
  BAR();
  SCHED0();

  #pragma unroll 1
  for (int i = 0; i < 16; ++i) {
    const size_t kP1 = (size_t)(2 * i + 1) * 64;                    // A1(t1): always real
    const size_t kT2 = (i < 15) ? (size_t)(2 * i + 2) * 64 : 0;     // t0+2 (dead @i=15)
    const size_t kT3 = (i < 15) ? (size_t)(2 * i + 3) * 64 : 0;     // t1+2 (dead @i=15)

    // ---- p1: quadrant (m0,n0) x t0 | reads A0+B0 (12) | stage A1(t1)
    READ_A(0, 0);
    READ_B(0, 0, b0);
    STAGE_A(1, 1, kP1);
    LGKM8();
    BAR();
    LGKM0();
    MFMA16(0, 0, b0);
    BAR(); SCHED0();

    // ---- p2: (m0,n1) x t0 | reads B1 (4) | stage A0(t0+2)
    READ_B(0, 1, b1);
    STAGE_A(0, 0, kT2);
    BAR();
    LGKM0();
    MFMA16(0, 1, b1);
    BAR(); SCHED0();

    // ---- p3: (m1,n0) x t0 | reads A1 (8) | stage B0(t0+2)
    READ_A(0, 1);
    STAGE_B(0, 0, kT2);
    BAR();
    LGKM0();
    MFMA16(1, 0, b0);
    BAR(); SCHED0();

    // ---- p4: (m1,n1) x t0 | no reads | stage B1(t0+2) | vmcnt(6)
    STAGE_B(0, 1, kT2);
    BAR();
    MFMA16(1, 1, b1);
    VM6();
    BAR(); SCHED0();

    // ---- p5: (m0,n0) x t1 | reads A0+B0 (12) | stage A1(t0+2)
    READ_A(1, 0);
    READ_B(1, 0, b0);
    STAGE_A(0, 1, kT2);
    LGKM8();
    BAR();
    LGKM0();
    MFMA16(0, 0, b0);
    BAR(); SCHED0();

    // ---- p6: (m0,n1) x t1 | reads B1 (4) | stage A0(t1+2)
    READ_B(1, 1, b1);
    STAGE_A(1, 0, kT3);
    BAR();
    LGKM0();
    MFMA16(0, 1, b1);
    BAR(); SCHED0();

    // ---- p7: (m1,n0) x t1 | reads A1 (8) | stage B0(t1+2)
    READ_A(1, 1);
    STAGE_B(1, 0, kT3);
    BAR();
    LGKM0();
    MFMA16(1, 0, b0);
    BAR(); SCHED0();

    // ---- p8: (m1,n1) x t1 | no reads | stage B1(t1+2) | vmcnt(6)
    STAGE_B(1, 1, kT3);
    BAR();
    MFMA16(1, 1, b1);
    VM6();
    BAR(); SCHED0();
  }

  // drain dead tail prefetches before exit (an in-flight LDS-DMA landing in a
  // successor block's LDS on this CU would corrupt it)
  asm volatile("s_waitcnt vmcnt(0)" ::: "memory");

  // ---------- epilogue: D lane map col=lane&15, row=(lane>>4)*4 + r
  // acc[a][b]: row off = (a>>2)*64 + (a&3)*16, col off = (b>>1)*32 + (b&1)*16
  const int row0 = bm * 256 + wm * 128 + lq * 4;
  const int col0 = bn * 256 + wn * 64 + lrow;
  #pragma unroll
  for (int a = 0; a < 8; ++a) {
    const int row = row0 + (a >> 2) * 64 + (a & 3) * 16;
    const f32x4 sc4 = *(const f32x4*)(scale + row);
    #pragma unroll
    for (int b2 = 0; b2 < 4; ++b2) {
      const int col = col0 + (b2 >> 1) * 32 + (b2 & 1) * 16;
      const float bcol = bias[col];
      #pragma unroll
      for (int r = 0; r < 4; ++r) {
        float v = acc[a][b2][r] * sc4[r] + bcol;
        out[(size_t)(row + r) * OUT_DIM + col] = fmaxf(v, 0.0f);
      }
    }
  }
}

extern "C" void kernel_launch(void* const* d_in, const int* in_sizes, int n_in,
                              void* d_out, int out_size, void* d_ws, size_t ws_size,
                              hipStream_t stream) {
  const float* x = (const float*)d_in[0];
  const float* W = (const float*)d_in[1];
  const float* b = (const float*)d_in[2];
  float* out = (float*)d_out;

  char* ws = (char*)d_ws;
  unsigned short* xn    = (unsigned short*)ws;                                  // 67108864 B
  unsigned short* Wb    = (unsigned short*)(ws + (size_t)67108864);             //  8388608 B
  float*          scale = (float*)(ws + (size_t)67108864 + (size_t)8388608);    //    65536 B

  prep_kernel<<<PREP_X_BLOCKS + PREP_W_BLOCKS, 256, 0, stream>>>(x, xn, scale, W, Wb);

  gemm_kernel<<<(OUT_DIM / 256) * (B_ROWS / 256), 512, 0, stream>>>(xn, Wb, scale, b, out);
}